// Round 1
// baseline (1347.661 us; speedup 1.0000x reference)
//
#include <hip/hip_runtime.h>
#include <math.h>

// Problem constants
#define BB 2
#define HH 64
#define WW 64
#define DM 192
#define DI 384
#define NS 16
#define DTR 12
#define LL 4096
#define ROWS (BB*LL)   // 8192

__device__ __forceinline__ float silu_f(float v) {
    return v / (1.0f + __expf(-v));
}

// ---------------------------------------------------------------------------
// Tiled fp32 GEMM: out[m,n] = sum_k A[m,K]*W[n,K]   (both K-major)
// mode 0: N=768 split -> out0[row*384+col] raw (col<384), out1[row*384+col-384]=silu
// mode 1: out0[row*N+col] plain
// BM=BN=64, BK=16, 256 threads, 4x4 per thread.
// ---------------------------------------------------------------------------
__global__ __launch_bounds__(256) void gemm_wT(
    const float* __restrict__ A, const float* __restrict__ W,
    float* __restrict__ out0, float* __restrict__ out1,
    int M, int N, int K, int mode)
{
    __shared__ float As[16][64];
    __shared__ float Ws[16][64];
    const int bm = blockIdx.x * 64;
    const int bn = blockIdx.y * 64;
    const int tid = threadIdx.x;
    const int tm = (tid >> 4) * 4;   // 0..60
    const int tn = (tid & 15) * 4;   // 0..60
    float acc[4][4];
    #pragma unroll
    for (int i = 0; i < 4; ++i)
        #pragma unroll
        for (int j = 0; j < 4; ++j) acc[i][j] = 0.f;

    const int r  = tid >> 2;        // 0..63
    const int kk = (tid & 3) * 4;   // 0,4,8,12

    for (int k0 = 0; k0 < K; k0 += 16) {
        float4 av = *(const float4*)&A[(size_t)(bm + r) * K + k0 + kk];
        float4 wv = *(const float4*)&W[(size_t)(bn + r) * K + k0 + kk];
        As[kk+0][r] = av.x; As[kk+1][r] = av.y; As[kk+2][r] = av.z; As[kk+3][r] = av.w;
        Ws[kk+0][r] = wv.x; Ws[kk+1][r] = wv.y; Ws[kk+2][r] = wv.z; Ws[kk+3][r] = wv.w;
        __syncthreads();
        #pragma unroll
        for (int k = 0; k < 16; ++k) {
            float4 a = *(const float4*)&As[k][tm];
            float4 b = *(const float4*)&Ws[k][tn];
            acc[0][0] += a.x*b.x; acc[0][1] += a.x*b.y; acc[0][2] += a.x*b.z; acc[0][3] += a.x*b.w;
            acc[1][0] += a.y*b.x; acc[1][1] += a.y*b.y; acc[1][2] += a.y*b.z; acc[1][3] += a.y*b.w;
            acc[2][0] += a.z*b.x; acc[2][1] += a.z*b.y; acc[2][2] += a.z*b.z; acc[2][3] += a.z*b.w;
            acc[3][0] += a.w*b.x; acc[3][1] += a.w*b.y; acc[3][2] += a.w*b.z; acc[3][3] += a.w*b.w;
        }
        __syncthreads();
    }

    #pragma unroll
    for (int i = 0; i < 4; ++i) {
        int row = bm + tm + i;
        #pragma unroll
        for (int j = 0; j < 4; ++j) {
            int col = bn + tn + j;
            float v = acc[i][j];
            if (mode == 0) {
                if (col < 384) out0[(size_t)row * 384 + col] = v;
                else           out1[(size_t)row * 384 + (col - 384)] = silu_f(v);
            } else {
                out0[(size_t)row * N + col] = v;
            }
        }
    }
}

// ---------------------------------------------------------------------------
// Depthwise 3x3 conv SAME + bias + silu. In/out layout (B, 4096, 384).
// grid (64 pixel tiles of 8x8, 6 channel groups of 64, B); 256 threads.
// ---------------------------------------------------------------------------
__global__ __launch_bounds__(256) void dwconv_silu(
    const float* __restrict__ in, const float* __restrict__ w,
    const float* __restrict__ bias, float* __restrict__ out)
{
    const int tile = blockIdx.x;
    const int c0   = blockIdx.y * 64;
    const int b    = blockIdx.z;
    const int h0 = (tile >> 3) * 8, w0 = (tile & 7) * 8;
    __shared__ float sm[10 * 10 * 64];   // [py][px][ch]

    for (int idx = threadIdx.x; idx < 6400; idx += 256) {
        int pix = idx >> 6, ch = idx & 63;
        int py = pix / 10, px = pix - py * 10;
        int gh = h0 + py - 1, gw = w0 + px - 1;
        float v = 0.f;
        if (gh >= 0 && gh < 64 && gw >= 0 && gw < 64)
            v = in[((size_t)(b * LL + gh * 64 + gw)) * DI + c0 + ch];
        sm[idx] = v;
    }
    __syncthreads();

    const int ch = threadIdx.x & 63;
    const int pq = threadIdx.x >> 6;   // 0..3
    float wr[9];
    #pragma unroll
    for (int k = 0; k < 9; ++k) wr[k] = w[(c0 + ch) * 9 + k];
    const float bv = bias[c0 + ch];

    #pragma unroll
    for (int i = 0; i < 16; ++i) {
        int p  = pq * 16 + i;      // 0..63
        int ph = p >> 3, pw = p & 7;
        float acc = bv;
        #pragma unroll
        for (int ki = 0; ki < 3; ++ki)
            #pragma unroll
            for (int kj = 0; kj < 3; ++kj)
                acc += wr[ki * 3 + kj] * sm[((ph + ki) * 10 + (pw + kj)) * 64 + ch];
        out[((size_t)(b * LL + (h0 + ph) * 64 + (w0 + pw))) * DI + c0 + ch] = silu_f(acc);
    }
}

// ---------------------------------------------------------------------------
// Gather by scan_path, x_proj (44x384), dt_proj (384x12) + softplus.
// grid (4096, B), 384 threads.
// Outputs: xs (b,j,384), delta (b,j,384), bt (b,j,16), ct (b,j,16)
// ---------------------------------------------------------------------------
__global__ __launch_bounds__(384) void gather_proj(
    const float* __restrict__ xa, const float* __restrict__ cc,
    const int* __restrict__ scan_path,
    const float* __restrict__ x_proj_w,   // (44,384)
    const float* __restrict__ dt_w,       // (384,12)
    const float* __restrict__ dt_b,       // (384,)
    float* __restrict__ xs, float* __restrict__ delta,
    float* __restrict__ bt, float* __restrict__ ct)
{
    const int j = blockIdx.x;
    const int b = blockIdx.y;
    const int l = scan_path[j];
    const int t = threadIdx.x;
    __shared__ float s[384];
    __shared__ float xd[44];
    __shared__ float part[352];

    const size_t src = ((size_t)(b * LL + l)) * DI;
    const size_t dst = ((size_t)(b * LL + j)) * DI;
    float xv = xa[src + t];
    float sv = xv + cc[src + t];
    s[t] = sv;
    xs[dst + t] = xv;
    __syncthreads();

    if (t < 352) {
        int c = t >> 3, p = t & 7;
        const float* wrow = x_proj_w + c * 384 + p * 48;
        const float* srow = s + p * 48;
        float a = 0.f;
        #pragma unroll
        for (int k = 0; k < 48; ++k) a += wrow[k] * srow[k];
        part[t] = a;
    }
    __syncthreads();
    if (t < 44) {
        float a = 0.f;
        #pragma unroll
        for (int p = 0; p < 8; ++p) a += part[t * 8 + p];
        xd[t] = a;
        size_t base = ((size_t)(b * LL + j)) * NS;
        if (t >= 12 && t < 28) bt[base + (t - 12)] = a;
        else if (t >= 28)      ct[base + (t - 28)] = a;
    }
    __syncthreads();

    float acc = dt_b[t];
    #pragma unroll
    for (int rr = 0; rr < DTR; ++rr) acc += dt_w[t * DTR + rr] * xd[rr];
    float d = (acc > 20.f) ? acc : log1pf(__expf(acc));
    delta[dst + t] = d;
}

// ---------------------------------------------------------------------------
// Sequential selective scan. 48 blocks x 256 threads.
// Block handles 16 channels of one batch; lane = (channel, n).
// ---------------------------------------------------------------------------
__global__ __launch_bounds__(256) void scan_kernel(
    const float* __restrict__ xs, const float* __restrict__ delta,
    const float* __restrict__ bt, const float* __restrict__ ct,
    const float* __restrict__ A_logs, const float* __restrict__ Ds,
    float* __restrict__ yt)
{
    const int blk = blockIdx.x;
    const int b  = blk / 24;
    const int d0 = (blk % 24) * 16;
    const int t  = threadIdx.x;
    const int dc = t >> 4;      // 0..15
    const int n  = t & 15;
    const int d  = d0 + dc;

    const float Av = -__expf(A_logs[d * NS + n]);
    const float Dv = Ds[d];
    float h = 0.f;

    const float* dl = delta + (size_t)b * LL * DI + d;
    const float* ul = xs    + (size_t)b * LL * DI + d;
    const float* bl = bt + (size_t)b * LL * NS + n;
    const float* cl = ct + (size_t)b * LL * NS + n;
    float* yl = yt + (size_t)b * LL * DI + d;

    float dv[4], uv[4], bv[4], cv[4];
    #pragma unroll
    for (int q = 0; q < 4; ++q) {
        dv[q] = dl[(size_t)q * DI]; uv[q] = ul[(size_t)q * DI];
        bv[q] = bl[(size_t)q * NS]; cv[q] = cl[(size_t)q * NS];
    }

    for (int j = 0; j < LL; j += 4) {
        float nd[4], nu[4], nb[4], nc[4];
        if (j + 4 < LL) {
            #pragma unroll
            for (int q = 0; q < 4; ++q) {
                size_t jj = (size_t)(j + 4 + q);
                nd[q] = dl[jj * DI]; nu[q] = ul[jj * DI];
                nb[q] = bl[jj * NS]; nc[q] = cl[jj * NS];
            }
        }
        #pragma unroll
        for (int q = 0; q < 4; ++q) {
            float dA = __expf(dv[q] * Av);
            h = dA * h + dv[q] * bv[q] * uv[q];
            float acc = h * cv[q];
            acc += __shfl_xor(acc, 8, 16);
            acc += __shfl_xor(acc, 4, 16);
            acc += __shfl_xor(acc, 2, 16);
            acc += __shfl_xor(acc, 1, 16);
            if (n == 0) yl[(size_t)(j + q) * DI] = acc + uv[q] * Dv;
        }
        #pragma unroll
        for (int q = 0; q < 4; ++q) { dv[q]=nd[q]; uv[q]=nu[q]; bv[q]=nb[q]; cv[q]=nc[q]; }
    }
}

// ---------------------------------------------------------------------------
// LayerNorm over d (384) + affine + z-mul; unpermute folded into write.
// grid (4096, B), 128 threads (3 elements each).
// ---------------------------------------------------------------------------
__global__ __launch_bounds__(128) void ln_mul(
    const float* __restrict__ yt, const float* __restrict__ z,
    const int* __restrict__ scan_path,
    const float* __restrict__ ln_w, const float* __restrict__ ln_b,
    float* __restrict__ yn)
{
    const int j = blockIdx.x;
    const int b = blockIdx.y;
    const int l = scan_path[j];
    const int t = threadIdx.x;
    const float* row = yt + ((size_t)(b * LL + j)) * DI;
    float v0 = row[t], v1 = row[t + 128], v2 = row[t + 256];
    float s  = v0 + v1 + v2;
    float s2 = v0*v0 + v1*v1 + v2*v2;
    #pragma unroll
    for (int off = 32; off > 0; off >>= 1) {
        s  += __shfl_down(s, off);
        s2 += __shfl_down(s2, off);
    }
    __shared__ float red[4];
    if ((t & 63) == 0) { red[(t >> 6) * 2] = s; red[(t >> 6) * 2 + 1] = s2; }
    __syncthreads();
    float S  = red[0] + red[2];
    float S2 = red[1] + red[3];
    float mu  = S * (1.0f / DI);
    float var = S2 * (1.0f / DI) - mu * mu;
    float inv = rsqrtf(var + 1e-5f);

    const float* zr = z  + ((size_t)(b * LL + l)) * DI;
    float*       o  = yn + ((size_t)(b * LL + l)) * DI;
    o[t]       = ((v0 - mu) * inv * ln_w[t]       + ln_b[t])       * zr[t];
    o[t + 128] = ((v1 - mu) * inv * ln_w[t + 128] + ln_b[t + 128]) * zr[t + 128];
    o[t + 256] = ((v2 - mu) * inv * ln_w[t + 256] + ln_b[t + 256]) * zr[t + 256];
}

// ---------------------------------------------------------------------------
extern "C" void kernel_launch(void* const* d_in, const int* in_sizes, int n_in,
                              void* d_out, int out_size, void* d_ws, size_t ws_size,
                              hipStream_t stream) {
    const float* x          = (const float*)d_in[0];
    const float* cond       = (const float*)d_in[1];
    const float* W_in       = (const float*)d_in[2];
    const float* W_con      = (const float*)d_in[3];
    const float* conv_w     = (const float*)d_in[4];
    const float* conv_b     = (const float*)d_in[5];
    const float* con_conv_w = (const float*)d_in[6];
    const float* con_conv_b = (const float*)d_in[7];
    const float* x_proj_w   = (const float*)d_in[8];
    const float* dt_proj_w  = (const float*)d_in[9];
    const float* dt_proj_b  = (const float*)d_in[10];
    const float* A_logs     = (const float*)d_in[11];
    const float* Ds         = (const float*)d_in[12];
    const float* ln_w       = (const float*)d_in[13];
    const float* ln_b       = (const float*)d_in[14];
    const float* W_out      = (const float*)d_in[15];
    const int*   scan_path  = (const int*)d_in[16];

    float* ws = (float*)d_ws;
    const size_t S = (size_t)BB * LL * DI;   // 3,145,728 floats
    float* xa_pre  = ws + 0 * S;   // reused later as yt
    float* z_silu  = ws + 1 * S;
    float* c_pre   = ws + 2 * S;   // reused later as yn
    float* xa_conv = ws + 3 * S;
    float* c_conv  = ws + 4 * S;
    float* xs_buf  = ws + 5 * S;
    float* dl_buf  = ws + 6 * S;
    float* bt_buf  = ws + 7 * S;
    float* ct_buf  = bt_buf + (size_t)BB * LL * NS;
    float* yt  = xa_pre;
    float* yn  = c_pre;

    // 1) xz = x @ W_in.T  -> xa_pre (raw), z_silu (silu)
    gemm_wT<<<dim3(ROWS / 64, 768 / 64), 256, 0, stream>>>(
        x, W_in, xa_pre, z_silu, ROWS, 768, DM, 0);
    // 2) c = cond @ W_con.T -> c_pre
    gemm_wT<<<dim3(ROWS / 64, 384 / 64), 256, 0, stream>>>(
        cond, W_con, c_pre, nullptr, ROWS, 384, DM, 1);
    // 3) depthwise convs + silu
    dwconv_silu<<<dim3(64, 6, BB), 256, 0, stream>>>(xa_pre, conv_w, conv_b, xa_conv);
    dwconv_silu<<<dim3(64, 6, BB), 256, 0, stream>>>(c_pre, con_conv_w, con_conv_b, c_conv);
    // 4) gather + projections
    gather_proj<<<dim3(LL, BB), 384, 0, stream>>>(
        xa_conv, c_conv, scan_path, x_proj_w, dt_proj_w, dt_proj_b,
        xs_buf, dl_buf, bt_buf, ct_buf);
    // 5) selective scan
    scan_kernel<<<48, 256, 0, stream>>>(
        xs_buf, dl_buf, bt_buf, ct_buf, A_logs, Ds, yt);
    // 6) LN + z-mul (unpermute folded in)
    ln_mul<<<dim3(LL, BB), 128, 0, stream>>>(yt, z_silu, scan_path, ln_w, ln_b, yn);
    // 7) out = yn @ W_out.T
    gemm_wT<<<dim3(ROWS / 64, 192 / 64), 256, 0, stream>>>(
        yn, W_out, (float*)d_out, nullptr, ROWS, DM, DI, 1);
}

// Round 2
// 343.049 us; speedup vs baseline: 3.9285x; 3.9285x over previous
//
#include <hip/hip_runtime.h>
#include <math.h>

// Problem constants
#define BB 2
#define HH 64
#define WW 64
#define DM 192
#define DI 384
#define NS 16
#define DTR 12
#define LL 4096
#define ROWS (BB*LL)   // 8192
#define NCHUNK 64
#define LCHUNK 64      // NCHUNK*LCHUNK == LL

__device__ __forceinline__ float silu_f(float v) {
    return v / (1.0f + __expf(-v));
}

// ---------------------------------------------------------------------------
// Tiled fp32 GEMM: out[m,n] = sum_k A[m,K]*W[n,K]   (both K-major)
// mode 0: N=768 split -> out0[row*384+col] raw (col<384), out1[row*384+col-384]=silu
// mode 1: out0[row*N+col] plain
// ---------------------------------------------------------------------------
__global__ __launch_bounds__(256) void gemm_wT(
    const float* __restrict__ A, const float* __restrict__ W,
    float* __restrict__ out0, float* __restrict__ out1,
    int M, int N, int K, int mode)
{
    __shared__ float As[16][64];
    __shared__ float Ws[16][64];
    const int bm = blockIdx.x * 64;
    const int bn = blockIdx.y * 64;
    const int tid = threadIdx.x;
    const int tm = (tid >> 4) * 4;
    const int tn = (tid & 15) * 4;
    float acc[4][4];
    #pragma unroll
    for (int i = 0; i < 4; ++i)
        #pragma unroll
        for (int j = 0; j < 4; ++j) acc[i][j] = 0.f;

    const int r  = tid >> 2;
    const int kk = (tid & 3) * 4;

    for (int k0 = 0; k0 < K; k0 += 16) {
        float4 av = *(const float4*)&A[(size_t)(bm + r) * K + k0 + kk];
        float4 wv = *(const float4*)&W[(size_t)(bn + r) * K + k0 + kk];
        As[kk+0][r] = av.x; As[kk+1][r] = av.y; As[kk+2][r] = av.z; As[kk+3][r] = av.w;
        Ws[kk+0][r] = wv.x; Ws[kk+1][r] = wv.y; Ws[kk+2][r] = wv.z; Ws[kk+3][r] = wv.w;
        __syncthreads();
        #pragma unroll
        for (int k = 0; k < 16; ++k) {
            float4 a = *(const float4*)&As[k][tm];
            float4 b = *(const float4*)&Ws[k][tn];
            acc[0][0] += a.x*b.x; acc[0][1] += a.x*b.y; acc[0][2] += a.x*b.z; acc[0][3] += a.x*b.w;
            acc[1][0] += a.y*b.x; acc[1][1] += a.y*b.y; acc[1][2] += a.y*b.z; acc[1][3] += a.y*b.w;
            acc[2][0] += a.z*b.x; acc[2][1] += a.z*b.y; acc[2][2] += a.z*b.z; acc[2][3] += a.z*b.w;
            acc[3][0] += a.w*b.x; acc[3][1] += a.w*b.y; acc[3][2] += a.w*b.z; acc[3][3] += a.w*b.w;
        }
        __syncthreads();
    }

    #pragma unroll
    for (int i = 0; i < 4; ++i) {
        int row = bm + tm + i;
        #pragma unroll
        for (int j = 0; j < 4; ++j) {
            int col = bn + tn + j;
            float v = acc[i][j];
            if (mode == 0) {
                if (col < 384) out0[(size_t)row * 384 + col] = v;
                else           out1[(size_t)row * 384 + (col - 384)] = silu_f(v);
            } else {
                out0[(size_t)row * N + col] = v;
            }
        }
    }
}

// ---------------------------------------------------------------------------
// Depthwise 3x3 conv SAME + bias + silu. In/out layout (B, 4096, 384).
// ---------------------------------------------------------------------------
__global__ __launch_bounds__(256) void dwconv_silu(
    const float* __restrict__ in, const float* __restrict__ w,
    const float* __restrict__ bias, float* __restrict__ out)
{
    const int tile = blockIdx.x;
    const int c0   = blockIdx.y * 64;
    const int b    = blockIdx.z;
    const int h0 = (tile >> 3) * 8, w0 = (tile & 7) * 8;
    __shared__ float sm[10 * 10 * 64];

    for (int idx = threadIdx.x; idx < 6400; idx += 256) {
        int pix = idx >> 6, ch = idx & 63;
        int py = pix / 10, px = pix - py * 10;
        int gh = h0 + py - 1, gw = w0 + px - 1;
        float v = 0.f;
        if (gh >= 0 && gh < 64 && gw >= 0 && gw < 64)
            v = in[((size_t)(b * LL + gh * 64 + gw)) * DI + c0 + ch];
        sm[idx] = v;
    }
    __syncthreads();

    const int ch = threadIdx.x & 63;
    const int pq = threadIdx.x >> 6;
    float wr[9];
    #pragma unroll
    for (int k = 0; k < 9; ++k) wr[k] = w[(c0 + ch) * 9 + k];
    const float bv = bias[c0 + ch];

    #pragma unroll
    for (int i = 0; i < 16; ++i) {
        int p  = pq * 16 + i;
        int ph = p >> 3, pw = p & 7;
        float acc = bv;
        #pragma unroll
        for (int ki = 0; ki < 3; ++ki)
            #pragma unroll
            for (int kj = 0; kj < 3; ++kj)
                acc += wr[ki * 3 + kj] * sm[((ph + ki) * 10 + (pw + kj)) * 64 + ch];
        out[((size_t)(b * LL + (h0 + ph) * 64 + (w0 + pw))) * DI + c0 + ch] = silu_f(acc);
    }
}

// ---------------------------------------------------------------------------
// Gather by scan_path, x_proj (44x384), dt_proj (384x12) + softplus.
// ---------------------------------------------------------------------------
__global__ __launch_bounds__(384) void gather_proj(
    const float* __restrict__ xa, const float* __restrict__ cc,
    const int* __restrict__ scan_path,
    const float* __restrict__ x_proj_w,
    const float* __restrict__ dt_w,
    const float* __restrict__ dt_b,
    float* __restrict__ xs, float* __restrict__ delta,
    float* __restrict__ bt, float* __restrict__ ct)
{
    const int j = blockIdx.x;
    const int b = blockIdx.y;
    const int l = scan_path[j];
    const int t = threadIdx.x;
    __shared__ float s[384];
    __shared__ float xd[44];
    __shared__ float part[352];

    const size_t src = ((size_t)(b * LL + l)) * DI;
    const size_t dst = ((size_t)(b * LL + j)) * DI;
    float xv = xa[src + t];
    float sv = xv + cc[src + t];
    s[t] = sv;
    xs[dst + t] = xv;
    __syncthreads();

    if (t < 352) {
        int c = t >> 3, p = t & 7;
        const float* wrow = x_proj_w + c * 384 + p * 48;
        const float* srow = s + p * 48;
        float a = 0.f;
        #pragma unroll
        for (int k = 0; k < 48; ++k) a += wrow[k] * srow[k];
        part[t] = a;
    }
    __syncthreads();
    if (t < 44) {
        float a = 0.f;
        #pragma unroll
        for (int p = 0; p < 8; ++p) a += part[t * 8 + p];
        xd[t] = a;
        size_t base = ((size_t)(b * LL + j)) * NS;
        if (t >= 12 && t < 28) bt[base + (t - 12)] = a;
        else if (t >= 28)      ct[base + (t - 28)] = a;
    }
    __syncthreads();

    float acc = dt_b[t];
    #pragma unroll
    for (int rr = 0; rr < DTR; ++rr) acc += dt_w[t * DTR + rr] * xd[rr];
    float d = (acc > 20.f) ? acc : log1pf(__expf(acc));
    delta[dst + t] = d;
}

// ---------------------------------------------------------------------------
// Chunked parallel scan — Pass A: per-chunk composite (A_c = prod dA, B_c =
// local h_end with h0=0). grid (NCHUNK, DI/16, BB), 256 threads.
// Output layout [c][b][d][n] so pass B strides cleanly.
// ---------------------------------------------------------------------------
__global__ __launch_bounds__(256) void scan_chunkA(
    const float* __restrict__ xs, const float* __restrict__ delta,
    const float* __restrict__ bt, const float* __restrict__ A_logs,
    float* __restrict__ chunkA, float* __restrict__ chunkB)
{
    const int c = blockIdx.x;
    const int g = blockIdx.y;
    const int b = blockIdx.z;
    const int t = threadIdx.x;
    const int dc = t >> 4, n = t & 15;
    const int d = g * 16 + dc;
    const float Av = -__expf(A_logs[d * NS + n]);
    const int j0 = c * LCHUNK;

    const float* dl = delta + (size_t)b * LL * DI + (size_t)j0 * DI + d;
    const float* ul = xs    + (size_t)b * LL * DI + (size_t)j0 * DI + d;
    const float* bl = bt    + (size_t)b * LL * NS + (size_t)j0 * NS + n;

    float h = 0.f, P = 1.f;
    float dv[4], uv[4], bv[4];
    #pragma unroll
    for (int q = 0; q < 4; ++q) {
        dv[q] = dl[(size_t)q * DI]; uv[q] = ul[(size_t)q * DI]; bv[q] = bl[(size_t)q * NS];
    }
    for (int j = 0; j < LCHUNK; j += 4) {
        float nd[4], nu[4], nb[4];
        if (j + 4 < LCHUNK) {
            #pragma unroll
            for (int q = 0; q < 4; ++q) {
                int jj = j + 4 + q;
                nd[q] = dl[(size_t)jj * DI]; nu[q] = ul[(size_t)jj * DI]; nb[q] = bl[(size_t)jj * NS];
            }
        }
        #pragma unroll
        for (int q = 0; q < 4; ++q) {
            float dA = __expf(dv[q] * Av);
            h = dA * h + dv[q] * bv[q] * uv[q];
            P *= dA;
        }
        #pragma unroll
        for (int q = 0; q < 4; ++q) { dv[q]=nd[q]; uv[q]=nu[q]; bv[q]=nb[q]; }
    }
    size_t idx = (((size_t)c * BB + b) * DI + d) * NS + n;
    chunkA[idx] = P;
    chunkB[idx] = h;
}

// ---------------------------------------------------------------------------
// Pass B: serial combine over chunks (tiny). 48 blocks x 256 threads.
// hstart[c][b][d][n] = state entering chunk c.
// ---------------------------------------------------------------------------
__global__ __launch_bounds__(256) void scan_combine(
    const float* __restrict__ chunkA, const float* __restrict__ chunkB,
    float* __restrict__ hstart)
{
    const int gid = blockIdx.x * 256 + threadIdx.x;   // 0..BB*DI*NS-1
    const size_t stride = (size_t)BB * DI * NS;
    float h = 0.f;
    float a = chunkA[gid], bv = chunkB[gid];
    for (int c = 0; c < NCHUNK; ++c) {
        float na = 0.f, nb = 0.f;
        if (c + 1 < NCHUNK) {
            na = chunkA[(size_t)(c + 1) * stride + gid];
            nb = chunkB[(size_t)(c + 1) * stride + gid];
        }
        hstart[(size_t)c * stride + gid] = h;
        h = a * h + bv;
        a = na; bv = nb;
    }
}

// ---------------------------------------------------------------------------
// Pass C: redo local scan seeded with hstart, emit y. Same grid as pass A.
// ---------------------------------------------------------------------------
__global__ __launch_bounds__(256) void scan_chunkC(
    const float* __restrict__ xs, const float* __restrict__ delta,
    const float* __restrict__ bt, const float* __restrict__ ct,
    const float* __restrict__ A_logs, const float* __restrict__ Ds,
    const float* __restrict__ hstart,
    float* __restrict__ yt)
{
    const int c = blockIdx.x;
    const int g = blockIdx.y;
    const int b = blockIdx.z;
    const int t = threadIdx.x;
    const int dc = t >> 4, n = t & 15;
    const int d = g * 16 + dc;
    const float Av = -__expf(A_logs[d * NS + n]);
    const float Dv = Ds[d];
    const int j0 = c * LCHUNK;

    const float* dl = delta + (size_t)b * LL * DI + (size_t)j0 * DI + d;
    const float* ul = xs    + (size_t)b * LL * DI + (size_t)j0 * DI + d;
    const float* bl = bt    + (size_t)b * LL * NS + (size_t)j0 * NS + n;
    const float* cl = ct    + (size_t)b * LL * NS + (size_t)j0 * NS + n;
    float* yl = yt + (size_t)b * LL * DI + (size_t)j0 * DI + d;

    float h = hstart[(((size_t)c * BB + b) * DI + d) * NS + n];

    float dv[4], uv[4], bv[4], cv[4];
    #pragma unroll
    for (int q = 0; q < 4; ++q) {
        dv[q] = dl[(size_t)q * DI]; uv[q] = ul[(size_t)q * DI];
        bv[q] = bl[(size_t)q * NS]; cv[q] = cl[(size_t)q * NS];
    }
    for (int j = 0; j < LCHUNK; j += 4) {
        float nd[4], nu[4], nb[4], nc[4];
        if (j + 4 < LCHUNK) {
            #pragma unroll
            for (int q = 0; q < 4; ++q) {
                int jj = j + 4 + q;
                nd[q] = dl[(size_t)jj * DI]; nu[q] = ul[(size_t)jj * DI];
                nb[q] = bl[(size_t)jj * NS]; nc[q] = cl[(size_t)jj * NS];
            }
        }
        #pragma unroll
        for (int q = 0; q < 4; ++q) {
            float dA = __expf(dv[q] * Av);
            h = dA * h + dv[q] * bv[q] * uv[q];
            float acc = h * cv[q];
            acc += __shfl_xor(acc, 8, 16);
            acc += __shfl_xor(acc, 4, 16);
            acc += __shfl_xor(acc, 2, 16);
            acc += __shfl_xor(acc, 1, 16);
            if (n == 0) yl[(size_t)(j + q) * DI] = acc + uv[q] * Dv;
        }
        #pragma unroll
        for (int q = 0; q < 4; ++q) { dv[q]=nd[q]; uv[q]=nu[q]; bv[q]=nb[q]; cv[q]=nc[q]; }
    }
}

// ---------------------------------------------------------------------------
// LayerNorm over d (384) + affine + z-mul; unpermute folded into write.
// ---------------------------------------------------------------------------
__global__ __launch_bounds__(128) void ln_mul(
    const float* __restrict__ yt, const float* __restrict__ z,
    const int* __restrict__ scan_path,
    const float* __restrict__ ln_w, const float* __restrict__ ln_b,
    float* __restrict__ yn)
{
    const int j = blockIdx.x;
    const int b = blockIdx.y;
    const int l = scan_path[j];
    const int t = threadIdx.x;
    const float* row = yt + ((size_t)(b * LL + j)) * DI;
    float v0 = row[t], v1 = row[t + 128], v2 = row[t + 256];
    float s  = v0 + v1 + v2;
    float s2 = v0*v0 + v1*v1 + v2*v2;
    #pragma unroll
    for (int off = 32; off > 0; off >>= 1) {
        s  += __shfl_down(s, off);
        s2 += __shfl_down(s2, off);
    }
    __shared__ float red[4];
    if ((t & 63) == 0) { red[(t >> 6) * 2] = s; red[(t >> 6) * 2 + 1] = s2; }
    __syncthreads();
    float S  = red[0] + red[2];
    float S2 = red[1] + red[3];
    float mu  = S * (1.0f / DI);
    float var = S2 * (1.0f / DI) - mu * mu;
    float inv = rsqrtf(var + 1e-5f);

    const float* zr = z  + ((size_t)(b * LL + l)) * DI;
    float*       o  = yn + ((size_t)(b * LL + l)) * DI;
    o[t]       = ((v0 - mu) * inv * ln_w[t]       + ln_b[t])       * zr[t];
    o[t + 128] = ((v1 - mu) * inv * ln_w[t + 128] + ln_b[t + 128]) * zr[t + 128];
    o[t + 256] = ((v2 - mu) * inv * ln_w[t + 256] + ln_b[t + 256]) * zr[t + 256];
}

// ---------------------------------------------------------------------------
extern "C" void kernel_launch(void* const* d_in, const int* in_sizes, int n_in,
                              void* d_out, int out_size, void* d_ws, size_t ws_size,
                              hipStream_t stream) {
    const float* x          = (const float*)d_in[0];
    const float* cond       = (const float*)d_in[1];
    const float* W_in       = (const float*)d_in[2];
    const float* W_con      = (const float*)d_in[3];
    const float* conv_w     = (const float*)d_in[4];
    const float* conv_b     = (const float*)d_in[5];
    const float* con_conv_w = (const float*)d_in[6];
    const float* con_conv_b = (const float*)d_in[7];
    const float* x_proj_w   = (const float*)d_in[8];
    const float* dt_proj_w  = (const float*)d_in[9];
    const float* dt_proj_b  = (const float*)d_in[10];
    const float* A_logs     = (const float*)d_in[11];
    const float* Ds         = (const float*)d_in[12];
    const float* ln_w       = (const float*)d_in[13];
    const float* ln_b       = (const float*)d_in[14];
    const float* W_out      = (const float*)d_in[15];
    const int*   scan_path  = (const int*)d_in[16];

    float* ws = (float*)d_ws;
    const size_t S = (size_t)BB * LL * DI;       // 3,145,728 floats
    const size_t SC = (size_t)NCHUNK * BB * DI * NS;  // 786,432 floats
    float* xa_pre  = ws + 0 * S;   // reused later as yt
    float* z_silu  = ws + 1 * S;
    float* c_pre   = ws + 2 * S;   // reused later as yn
    float* xa_conv = ws + 3 * S;
    float* c_conv  = ws + 4 * S;
    float* xs_buf  = ws + 5 * S;
    float* dl_buf  = ws + 6 * S;
    float* bt_buf  = ws + 7 * S;
    float* ct_buf  = bt_buf + (size_t)BB * LL * NS;
    float* chunkA  = ws + 8 * S;             // conv buffers dead by then, but append to be safe
    float* chunkB  = chunkA + SC;
    float* hstart  = chunkB + SC;
    float* yt  = xa_pre;
    float* yn  = c_pre;

    // 1) xz = x @ W_in.T  -> xa_pre (raw), z_silu (silu)
    gemm_wT<<<dim3(ROWS / 64, 768 / 64), 256, 0, stream>>>(
        x, W_in, xa_pre, z_silu, ROWS, 768, DM, 0);
    // 2) c = cond @ W_con.T -> c_pre
    gemm_wT<<<dim3(ROWS / 64, 384 / 64), 256, 0, stream>>>(
        cond, W_con, c_pre, nullptr, ROWS, 384, DM, 1);
    // 3) depthwise convs + silu
    dwconv_silu<<<dim3(64, 6, BB), 256, 0, stream>>>(xa_pre, conv_w, conv_b, xa_conv);
    dwconv_silu<<<dim3(64, 6, BB), 256, 0, stream>>>(c_pre, con_conv_w, con_conv_b, c_conv);
    // 4) gather + projections
    gather_proj<<<dim3(LL, BB), 384, 0, stream>>>(
        xa_conv, c_conv, scan_path, x_proj_w, dt_proj_w, dt_proj_b,
        xs_buf, dl_buf, bt_buf, ct_buf);
    // 5) chunked parallel scan (3 passes)
    scan_chunkA<<<dim3(NCHUNK, DI / 16, BB), 256, 0, stream>>>(
        xs_buf, dl_buf, bt_buf, A_logs, chunkA, chunkB);
    scan_combine<<<(BB * DI * NS) / 256, 256, 0, stream>>>(chunkA, chunkB, hstart);
    scan_chunkC<<<dim3(NCHUNK, DI / 16, BB), 256, 0, stream>>>(
        xs_buf, dl_buf, bt_buf, ct_buf, A_logs, Ds, hstart, yt);
    // 6) LN + z-mul (unpermute folded in)
    ln_mul<<<dim3(LL, BB), 128, 0, stream>>>(yt, z_silu, scan_path, ln_w, ln_b, yn);
    // 7) out = yn @ W_out.T
    gemm_wT<<<dim3(ROWS / 64, 192 / 64), 256, 0, stream>>>(
        yn, W_out, (float*)d_out, nullptr, ROWS, DM, DI, 1);
}